// Round 1
// baseline (49.335 us; speedup 1.0000x reference)
//
#include <hip/hip_runtime.h>
#include <math.h>

// Problem constants (fixed by the reference)
constexpr int B = 8192;
constexpr int D = 128;
constexpr int K = 256;
constexpr int MAIN_BLOCKS = 512;         // 2 blocks/CU; 16 rows each
constexpr int ROWS = B / MAIN_BLOCKS;    // 16

// --- Kernel 1: hh[b] = sum_d h[b][d]^2 ------------------------------------
__global__ __launch_bounds__(256) void hh_kernel(const float* __restrict__ h,
                                                 float* __restrict__ hh) {
  const int wid  = threadIdx.x >> 6;
  const int lane = threadIdx.x & 63;
  const int b = blockIdx.x * 4 + wid;
  const float* hb = h + (size_t)b * D;
  float v0 = hb[lane];
  float v1 = hb[lane + 64];
  float s = v0 * v0 + v1 * v1;
#pragma unroll
  for (int off = 32; off; off >>= 1) s += __shfl_xor(s, off);
  if (lane == 0) hh[b] = s;
}

// --- Kernel 2: part_reg[i] = -log(min_{j!=i} ||c_i - c_j||^2) --------------
__global__ __launch_bounds__(256) void reg_kernel(const float* __restrict__ centers,
                                                  float* __restrict__ part_reg) {
  const int i = blockIdx.x;
  const int j = threadIdx.x;
  const float* ci = centers + (size_t)i * D;  // uniform -> scalar loads
  const float* cj = centers + (size_t)j * D;  // per-lane
  float pd = 0.f;
#pragma unroll
  for (int q = 0; q < D / 4; ++q) {
    float4 a  = reinterpret_cast<const float4*>(ci)[q];
    float4 bq = reinterpret_cast<const float4*>(cj)[q];
    float dx = a.x - bq.x, dy = a.y - bq.y, dz = a.z - bq.z, dw = a.w - bq.w;
    pd = fmaf(dx, dx, fmaf(dy, dy, fmaf(dz, dz, fmaf(dw, dw, pd))));
  }
  if (j == i) pd = INFINITY;
  const int lane = threadIdx.x & 63;
  const int wid  = threadIdx.x >> 6;
#pragma unroll
  for (int off = 32; off; off >>= 1) pd = fminf(pd, __shfl_xor(pd, off));
  __shared__ float red[4];
  if (lane == 0) red[wid] = pd;
  __syncthreads();
  if (threadIdx.x == 0) {
    float m = fminf(fminf(red[0], red[1]), fminf(red[2], red[3]));
    part_reg[i] = -logf(m);
  }
}

// --- Kernel 3: main — per-row distances + logsumexp ------------------------
// Each thread t register-caches centroid row t (128 VGPRs). Per batch row:
// 128 fully-unrolled FMAs with wave-uniform scalar h loads, then block
// logsumexp over the 256 per-thread distances.
__global__ __launch_bounds__(256, 2) void main_kernel(
    const float* __restrict__ h, const int* __restrict__ y,
    const float* __restrict__ centers, const float* __restrict__ hh,
    float* __restrict__ part_loss) {
  const int t = threadIdx.x;

  float creg[D];
  const float4* crow = reinterpret_cast<const float4*>(centers + (size_t)t * D);
#pragma unroll
  for (int q = 0; q < D / 4; ++q) {
    float4 v = crow[q];
    creg[4 * q + 0] = v.x;
    creg[4 * q + 1] = v.y;
    creg[4 * q + 2] = v.z;
    creg[4 * q + 3] = v.w;
  }
  float cc = 0.f;
#pragma unroll
  for (int d = 0; d < D; ++d) cc = fmaf(creg[d], creg[d], cc);

  const int lane = t & 63;
  const int wid  = t >> 6;
  __shared__ float red[4];
  __shared__ float s_disty;
  float acc = 0.f;
  const int row0 = blockIdx.x * ROWS;

  for (int r = 0; r < ROWS; ++r) {
    const int b = row0 + r;
    const float* hb = h + (size_t)b * D;  // uniform address -> scalar loads
    float dot = 0.f;
#pragma unroll
    for (int d = 0; d < D; ++d) dot = fmaf(hb[d], creg[d], dot);
    float dist = fmaxf(hh[b] + cc - 2.f * dot, 0.f);

    if (t == y[b]) s_disty = dist;  // exactly one thread writes

    float negs = -sqrtf(dist);
    // block max of negs
    float m = negs;
#pragma unroll
    for (int off = 32; off; off >>= 1) m = fmaxf(m, __shfl_xor(m, off));
    if (lane == 0) red[wid] = m;
    __syncthreads();
    m = fmaxf(fmaxf(red[0], red[1]), fmaxf(red[2], red[3]));

    float p = __expf(negs - m);
#pragma unroll
    for (int off = 32; off; off >>= 1) p += __shfl_xor(p, off);
    __syncthreads();  // everyone done reading red before rewrite
    if (lane == 0) red[wid] = p;
    __syncthreads();
    if (t == 0) {
      float ssum = red[0] + red[1] + red[2] + red[3];
      acc += s_disty + m + __logf(ssum);
    }
    __syncthreads();  // protect s_disty/red for next row
  }
  if (t == 0) part_loss[blockIdx.x] = acc;
}

// --- Kernel 4: final deterministic reduction -------------------------------
__global__ __launch_bounds__(256) void final_kernel(
    const float* __restrict__ part_loss, const float* __restrict__ part_reg,
    float* __restrict__ out) {
  const int t = threadIdx.x;
  float v = (part_loss[t] + part_loss[t + K]) * (1.0f / (float)B) + part_reg[t];
  const int lane = t & 63;
  const int wid  = t >> 6;
#pragma unroll
  for (int off = 32; off; off >>= 1) v += __shfl_xor(v, off);
  __shared__ float red[4];
  if (lane == 0) red[wid] = v;
  __syncthreads();
  if (t == 0) out[0] = red[0] + red[1] + red[2] + red[3];
}

extern "C" void kernel_launch(void* const* d_in, const int* in_sizes, int n_in,
                              void* d_out, int out_size, void* d_ws, size_t ws_size,
                              hipStream_t stream) {
  const float* h       = (const float*)d_in[0];
  const int*   y       = (const int*)d_in[1];
  const float* centers = (const float*)d_in[2];
  float* out = (float*)d_out;
  float* ws  = (float*)d_ws;

  float* hh        = ws;                    // B floats
  float* part_loss = ws + B;                // MAIN_BLOCKS floats
  float* part_reg  = ws + B + MAIN_BLOCKS;  // K floats

  hh_kernel<<<B / 4, 256, 0, stream>>>(h, hh);
  reg_kernel<<<K, 256, 0, stream>>>(centers, part_reg);
  main_kernel<<<MAIN_BLOCKS, 256, 0, stream>>>(h, y, centers, hh, part_loss);
  final_kernel<<<1, 256, 0, stream>>>(part_loss, part_reg, out);
}

// Round 2
// 35.700 us; speedup vs baseline: 1.3819x; 1.3819x over previous
//
#include <hip/hip_runtime.h>
#include <math.h>

// Problem constants (fixed by the reference)
constexpr int B = 8192;
constexpr int D = 128;
constexpr int K = 256;
constexpr int CHUNKS = 16;        // k-dimension split
constexpr int KC = K / CHUNKS;    // 16 centroids per chunk
constexpr int RB = B / 256;       // 32 row-blocks of 256 threads

// ws layout (floats)
//   cc        : [0, 256)
//   part_reg  : [256, 512)
//   part_loss : [512, 544)
//   disty     : [1024, 1024+B)
//   s_part    : [1024+B, 1024+B+CHUNKS*B)

// --- Kernel 1: reg term + cc byproduct -------------------------------------
// block i: pd(i,j) over threads j; also thread j computes cc_j = ||c_j||^2
// (block 0 writes it).
__global__ __launch_bounds__(256) void reg_kernel(const float* __restrict__ centers,
                                                  float* __restrict__ part_reg,
                                                  float* __restrict__ cc) {
  const int i = blockIdx.x;
  const int j = threadIdx.x;
  const float* ci = centers + (size_t)i * D;  // uniform -> scalar loads
  const float* cj = centers + (size_t)j * D;  // per-lane
  float pd = 0.f, ccj = 0.f;
#pragma unroll
  for (int q = 0; q < D / 4; ++q) {
    float4 a  = reinterpret_cast<const float4*>(ci)[q];
    float4 bq = reinterpret_cast<const float4*>(cj)[q];
    float dx = a.x - bq.x, dy = a.y - bq.y, dz = a.z - bq.z, dw = a.w - bq.w;
    pd = fmaf(dx, dx, fmaf(dy, dy, fmaf(dz, dz, fmaf(dw, dw, pd))));
    ccj = fmaf(bq.x, bq.x, fmaf(bq.y, bq.y, fmaf(bq.z, bq.z, fmaf(bq.w, bq.w, ccj))));
  }
  if (i == 0) cc[j] = ccj;
  if (j == i) pd = INFINITY;
  const int lane = threadIdx.x & 63;
  const int wid  = threadIdx.x >> 6;
#pragma unroll
  for (int off = 32; off; off >>= 1) pd = fminf(pd, __shfl_xor(pd, off));
  __shared__ float red[4];
  if (lane == 0) red[wid] = pd;
  __syncthreads();
  if (threadIdx.x == 0) {
    float m = fminf(fminf(red[0], red[1]), fminf(red[2], red[3]));
    part_reg[i] = -logf(m);
  }
}

// --- Kernel 2: main — one batch row per thread, k-chunked ------------------
// Thread holds its h-row in 128 VGPRs (pinned via empty asm). Centroid chunk
// read via wave-uniform scalar loads. Online exp-sum fully in-thread: no
// barriers, no LDS, no shuffles in the hot loop. negs in [-25, 0] so no
// max-shift is needed for fp32 logsumexp.
__global__ __launch_bounds__(256, 2) void main_kernel(
    const float* __restrict__ h, const int* __restrict__ y,
    const float* __restrict__ centers, const float* __restrict__ cc,
    float* __restrict__ s_part, float* __restrict__ disty) {
  const int t = threadIdx.x;
  const int rb = blockIdx.x & (RB - 1);
  const int chunk = blockIdx.x / RB;
  const int b = rb * 256 + t;

  // Load h row into registers and pin it there.
  float hv[D];
  const float4* hrow = reinterpret_cast<const float4*>(h + (size_t)b * D);
#pragma unroll
  for (int q = 0; q < D / 4; ++q) {
    float4 v = hrow[q];
    hv[4 * q + 0] = v.x;
    hv[4 * q + 1] = v.y;
    hv[4 * q + 2] = v.z;
    hv[4 * q + 3] = v.w;
  }
#pragma unroll
  for (int d = 0; d < D; ++d) asm volatile("" : "+v"(hv[d]));

  float hh = 0.f;
#pragma unroll
  for (int d = 0; d < D; ++d) hh = fmaf(hv[d], hv[d], hh);

  const int yb = y[b];
  float s = 0.f;
  float dy = 0.f;
  const int k0 = chunk * KC;

#pragma unroll 2
  for (int kk = 0; kk < KC; ++kk) {
    const int k = k0 + kk;
    const float* ck = centers + (size_t)k * D;  // uniform -> scalar loads
    float dot = 0.f;
#pragma unroll
    for (int d = 0; d < D; ++d) dot = fmaf(ck[d], hv[d], dot);
    float dist = fmaxf(hh + cc[k] - 2.f * dot, 0.f);
    if (k == yb) dy = dist;
    s += __expf(-sqrtf(dist));
  }

  s_part[(size_t)chunk * B + b] = s;
  if (yb / KC == chunk) disty[b] = dy;
}

// --- Kernel 3: combine per-chunk partials into per-block loss sums ---------
__global__ __launch_bounds__(256) void combine_kernel(
    const float* __restrict__ s_part, const float* __restrict__ disty,
    float* __restrict__ part_loss) {
  const int t = threadIdx.x;
  const int b = blockIdx.x * 256 + t;
  float s = 0.f;
#pragma unroll
  for (int c = 0; c < CHUNKS; ++c) s += s_part[(size_t)c * B + b];
  float v = disty[b] + logf(s);
  const int lane = t & 63;
  const int wid  = t >> 6;
#pragma unroll
  for (int off = 32; off; off >>= 1) v += __shfl_xor(v, off);
  __shared__ float red[4];
  if (lane == 0) red[wid] = v;
  __syncthreads();
  if (t == 0) part_loss[blockIdx.x] = red[0] + red[1] + red[2] + red[3];
}

// --- Kernel 4: final deterministic reduction -------------------------------
__global__ __launch_bounds__(256) void final_kernel(
    const float* __restrict__ part_loss, const float* __restrict__ part_reg,
    float* __restrict__ out) {
  const int t = threadIdx.x;
  float v = part_reg[t] + (t < RB ? part_loss[t] * (1.0f / (float)B) : 0.f);
  const int lane = t & 63;
  const int wid  = t >> 6;
#pragma unroll
  for (int off = 32; off; off >>= 1) v += __shfl_xor(v, off);
  __shared__ float red[4];
  if (lane == 0) red[wid] = v;
  __syncthreads();
  if (t == 0) out[0] = red[0] + red[1] + red[2] + red[3];
}

extern "C" void kernel_launch(void* const* d_in, const int* in_sizes, int n_in,
                              void* d_out, int out_size, void* d_ws, size_t ws_size,
                              hipStream_t stream) {
  const float* h       = (const float*)d_in[0];
  const int*   y       = (const int*)d_in[1];
  const float* centers = (const float*)d_in[2];
  float* out = (float*)d_out;
  float* ws  = (float*)d_ws;

  float* cc        = ws;
  float* part_reg  = ws + 256;
  float* part_loss = ws + 512;
  float* disty     = ws + 1024;
  float* s_part    = ws + 1024 + B;

  reg_kernel<<<K, 256, 0, stream>>>(centers, part_reg, cc);
  main_kernel<<<RB * CHUNKS, 256, 0, stream>>>(h, y, centers, cc, s_part, disty);
  combine_kernel<<<RB, 256, 0, stream>>>(s_part, disty, part_loss);
  final_kernel<<<1, 256, 0, stream>>>(part_loss, part_reg, out);
}